// Round 1
// baseline (5266.973 us; speedup 1.0000x reference)
//
#include <hip/hip_runtime.h>
#include <cstdio>

// ---------------------------------------------------------------------------
// HypRelEncoder (StarE/QUAD-style 2-layer CompGCN with qualifiers) on gfx950.
// Strategy:
//   rel_e[e] = ALPHA*rel_all[etype[e]]                (init_rel_e kernel)
//            + (1-ALPHA) * sum_{quals q of e} (x[q_e]*rel_all[q_r]) @ w_q
//              -> GEMM over NQ qual rows (bf16 MFMA) with atomic-scatter epilogue
//   node_acc += scatter_dst( (norm * x[src] * rel_e) @ w ) / 3
//              -> GEMM over E edge rows; A-tile built on the fly in LDS
//   node_acc  = loop GEMM plain-write (runs first, so no memset needed)
//   x_next    = tanh(node_acc + bias)
//   r_next    = rel_all[:200] @ w_rel
// All GEMMs: 64 rows/block, bf16 A staged in LDS (K padded to 224),
// B = weight^T padded [208][224] bf16, v_mfma_f32_16x16x32_bf16, fp32 accum.
// ---------------------------------------------------------------------------

#define ALPHA_MIX 0.8f

constexpr int N_ENT  = 200000;
constexpr int D_     = 200;
constexpr int E_DIR_ = 500000;
constexpr int NQ_    = 400000;
constexpr int B_     = 4096;

constexpr int NT_  = 13;   // column tiles of 16 (208 padded, 200 used)
constexpr int LDA_ = 232;  // LDS A row stride (bf16 elements)
constexpr int WLD_ = 224;  // Bp row stride = padded K (7 * 32)

// d_out float offsets
constexpr size_t OFS_SUB  = 0;
constexpr size_t OFS_REL  = 819200;
constexpr size_t OFS_QOBJ = 1638400;
constexpr size_t OFS_QREL = 6553600;
constexpr size_t OFS_X    = 11468800;
constexpr size_t OFS_R    = 51468800;

typedef __bf16 bf16x8 __attribute__((ext_vector_type(8)));
typedef float  f32x4  __attribute__((ext_vector_type(4)));

__device__ __forceinline__ unsigned int f2bf(float f) {
  unsigned int u = __float_as_uint(f);
  u += 0x7FFFu + ((u >> 16) & 1u);   // round-to-nearest-even
  return u >> 16;
}
__device__ __forceinline__ unsigned long long pack4bf(float x, float y, float z, float w) {
  return (unsigned long long)f2bf(x) | ((unsigned long long)f2bf(y) << 16) |
         ((unsigned long long)f2bf(z) << 32) | ((unsigned long long)f2bf(w) << 48);
}

// ---------------------------------------------------------------------------
// Fused gather-GEMM.  MODE_A: how A rows are built (0: qual msg x[g]*rall[r],
// 1: norm*x[src]*rel_e, 2: x[row]*loop_rel, 3: plain rall[row]).
// EPI_ATOMIC: 1 -> atomicAdd into Out[out_idx[row]], 0 -> plain Out[row].
// ---------------------------------------------------------------------------
template<int MODE_A, int EPI_ATOMIC>
__global__ __launch_bounds__(256)
void gemm_fused(const float* __restrict__ X, const float* __restrict__ R,
                const int* __restrict__ idx_g, const int* __restrict__ idx_r,
                const float* __restrict__ normv,
                const unsigned short* __restrict__ Bp,
                float* __restrict__ Out, const int* __restrict__ out_idx,
                float scale, int nrows)
{
  __shared__ __align__(16) unsigned short As[64 * LDA_];
  __shared__ int   s_g[64];
  __shared__ int   s_r[64];
  __shared__ float s_sc[64];

  const int t  = threadIdx.x;
  const int r0 = blockIdx.x * 64;

  if (t < 64) {
    int rr = r0 + t;
    int cr = min(rr, nrows - 1);
    if (MODE_A == 0)      { s_g[t] = idx_g[cr]; s_r[t] = idx_r[cr]; }
    else if (MODE_A == 1) { s_g[t] = idx_g[cr]; s_sc[t] = (rr < nrows) ? normv[cr] : 0.0f; }
    else                  { s_g[t] = cr; }
  }
  __syncthreads();

  // build A tile: 64 rows x 200 cols (float4 granularity), bf16 into LDS
  for (int task = t; task < 64 * 50; task += 256) {
    int i = task / 50, c = task % 50;
    float ax, ay, az, aw;
    if (MODE_A == 0) {
      float4 xv = ((const float4*)(X + (size_t)s_g[i] * D_))[c];
      float4 rv = ((const float4*)(R + (size_t)s_r[i] * D_))[c];
      ax = xv.x * rv.x; ay = xv.y * rv.y; az = xv.z * rv.z; aw = xv.w * rv.w;
    } else if (MODE_A == 1) {
      int er = min(r0 + i, nrows - 1);
      float4 xv = ((const float4*)(X + (size_t)s_g[i] * D_))[c];
      float4 rv = ((const float4*)(R + (size_t)er * D_))[c];
      float sc = s_sc[i];
      ax = xv.x * rv.x * sc; ay = xv.y * rv.y * sc;
      az = xv.z * rv.z * sc; aw = xv.w * rv.w * sc;
    } else if (MODE_A == 2) {
      float4 xv = ((const float4*)(X + (size_t)s_g[i] * D_))[c];
      float4 rv = ((const float4*)R)[c];
      ax = xv.x * rv.x; ay = xv.y * rv.y; az = xv.z * rv.z; aw = xv.w * rv.w;
    } else {
      float4 xv = ((const float4*)(X + (size_t)s_g[i] * D_))[c];
      ax = xv.x; ay = xv.y; az = xv.z; aw = xv.w;
    }
    *(unsigned long long*)&As[i * LDA_ + c * 4] = pack4bf(ax, ay, az, aw);
  }
  // zero pad K range [200, 224)
  for (int task = t; task < 64 * 6; task += 256) {
    int i = task / 6, c = task % 6;
    *(unsigned long long*)&As[i * LDA_ + 200 + c * 4] = 0ull;
  }
  __syncthreads();

  const int wave = t >> 6, lane = t & 63;
  const int m = lane & 15, quad = lane >> 4;

  f32x4 acc[NT_];
  const f32x4 zero = {0.0f, 0.0f, 0.0f, 0.0f};
  #pragma unroll
  for (int i = 0; i < NT_; i++) acc[i] = zero;

  const unsigned short* arow = As + (wave * 16 + m) * LDA_ + quad * 8;
  const unsigned short* brow = Bp + (size_t)m * WLD_ + quad * 8;

  #pragma unroll
  for (int ks = 0; ks < 7; ks++) {
    bf16x8 av = *(const bf16x8*)(arow + ks * 32);
    #pragma unroll
    for (int tt = 0; tt < NT_; tt++) {
      bf16x8 bv = *(const bf16x8*)(brow + (size_t)tt * 16 * WLD_ + ks * 32);
      acc[tt] = __builtin_amdgcn_mfma_f32_16x16x32_bf16(av, bv, acc[tt], 0, 0, 0);
    }
  }

  // epilogue: C/D layout col = lane&15, row = quad*4 + reg  [m89-verified]
  #pragma unroll
  for (int rg = 0; rg < 4; rg++) {
    int row = r0 + wave * 16 + quad * 4 + rg;
    if (row < nrows) {
      size_t orow = EPI_ATOMIC ? (size_t)out_idx[row] * D_ : (size_t)row * D_;
      #pragma unroll
      for (int tt = 0; tt < NT_; tt++) {
        int col = tt * 16 + m;
        if (col < D_) {
          float v = acc[tt][rg] * scale;
          if (EPI_ATOMIC) atomicAdd(Out + orow + col, v);
          else            Out[orow + col] = v;
        }
      }
    }
  }
}

// ---------------------------------------------------------------------------
struct WP10 { const float* p[10]; };

__global__ void convert_weights(WP10 wp, unsigned short* __restrict__ wbp) {
  int i = blockIdx.x * 256 + threadIdx.x;
  if (i < 10 * 208 * WLD_) {
    int j = i / (208 * WLD_);
    int rem = i % (208 * WLD_);
    int n = rem / WLD_, k = rem % WLD_;
    float v = (n < D_ && k < D_) ? wp.p[j][(size_t)k * D_ + n] : 0.0f;  // Bp[n][k] = w[k][n]
    wbp[i] = (unsigned short)f2bf(v);
  }
}

__global__ void build_rall(const float* __restrict__ rel_embs,
                           const float* __restrict__ loop_rel,
                           float* __restrict__ rall) {
  int i = blockIdx.x * 256 + threadIdx.x;
  if (i < 201 * D_) rall[i] = (i < 200 * D_) ? rel_embs[i] : loop_rel[i - 200 * D_];
}

__global__ void copy_row(const float* __restrict__ src, float* __restrict__ dst, int n) {
  int i = blockIdx.x * 256 + threadIdx.x;
  if (i < n) dst[i] = src[i];
}

__global__ void deg_count(const int* __restrict__ src, int* __restrict__ deg, int E) {
  int e = blockIdx.x * 256 + threadIdx.x;
  if (e < E) atomicAdd(&deg[src[e]], 1);
}

__global__ void norm_build(const int* __restrict__ src, const int* __restrict__ dst,
                           const int* __restrict__ deg, float* __restrict__ nrm, int E) {
  int e = blockIdx.x * 256 + threadIdx.x;
  if (e < E) {
    int a = deg[src[e]], b = deg[dst[e]];
    float fa = (a > 0) ? rsqrtf((float)a) : 0.0f;
    float fb = (b > 0) ? rsqrtf((float)b) : 0.0f;
    nrm[e] = fa * fb;
  }
}

__global__ void init_rel_e_k(const float* __restrict__ rall, const int* __restrict__ etype,
                             float* __restrict__ rel_e) {
  int i = blockIdx.x * 256 + threadIdx.x;
  if (i < E_DIR_ * 50) {
    int e = i / 50, c = i % 50;
    float4 v = ((const float4*)(rall + (size_t)etype[e] * D_))[c];
    float4 o = make_float4(v.x * ALPHA_MIX, v.y * ALPHA_MIX, v.z * ALPHA_MIX, v.w * ALPHA_MIX);
    ((float4*)(rel_e + (size_t)e * D_))[c] = o;
  }
}

__global__ void final_tanh(const float* __restrict__ acc, const float* __restrict__ bias,
                           float* __restrict__ xo) {
  int i = blockIdx.x * 256 + threadIdx.x;
  if (i < N_ENT * 50) {
    int c = (i % 50) * 4;
    float4 a = ((const float4*)acc)[i];
    float4 b = *(const float4*)(bias + c);
    float4 o = make_float4(tanhf(a.x + b.x), tanhf(a.y + b.y),
                           tanhf(a.z + b.z), tanhf(a.w + b.w));
    ((float4*)xo)[i] = o;
  }
}

__global__ void gather_out(const float* __restrict__ x2, const float* __restrict__ r2,
                           const int* __restrict__ ent_ix, const int* __restrict__ rel_ix,
                           const int* __restrict__ quals_ix, float* __restrict__ out) {
  int i = blockIdx.x * 256 + threadIdx.x;
  if (i >= B_ * 14 * 50) return;
  int b = i / 700, rem = i % 700, slot = rem / 50, c = rem % 50;
  const float* srcrow; float* dstrow;
  if (slot == 0)      { srcrow = x2 + (size_t)ent_ix[b] * D_;  dstrow = out + OFS_SUB + (size_t)b * D_; }
  else if (slot == 1) { srcrow = r2 + (size_t)rel_ix[b] * D_;  dstrow = out + OFS_REL + (size_t)b * D_; }
  else if (slot < 8)  { int j = slot - 2;
                        srcrow = x2 + (size_t)quals_ix[b * 12 + 2 * j + 1] * D_;
                        dstrow = out + OFS_QOBJ + ((size_t)b * 6 + j) * D_; }
  else                { int j = slot - 8;
                        srcrow = r2 + (size_t)quals_ix[b * 12 + 2 * j] * D_;
                        dstrow = out + OFS_QREL + ((size_t)b * 6 + j) * D_; }
  ((float4*)dstrow)[c] = ((const float4*)srcrow)[c];
}

// ---------------------------------------------------------------------------
extern "C" void kernel_launch(void* const* d_in, const int* in_sizes, int n_in,
                              void* d_out, int out_size, void* d_ws, size_t ws_size,
                              hipStream_t stream)
{
  const float* ent       = (const float*)d_in[0];
  const float* rel_embs  = (const float*)d_in[1];
  // d_in[2..11] = w_in1,w_out1,w_loop1,w_rel1,w_q1,w_in2,w_out2,w_loop2,w_rel2,w_q2
  const float* loop_rel1 = (const float*)d_in[12];
  const float* loop_rel2 = (const float*)d_in[13];
  const float* b1        = (const float*)d_in[14];
  const float* b2        = (const float*)d_in[15];
  const int*   ei        = (const int*)d_in[16];
  const int*   etype     = (const int*)d_in[17];
  const int*   quals     = (const int*)d_in[18];
  const int*   ent_ix    = (const int*)d_in[19];
  const int*   rel_ix    = (const int*)d_in[20];
  const int*   quals_ix  = (const int*)d_in[21];

  // workspace layout
  char* wsb = (char*)d_ws;
  size_t off = 0;
  auto walloc = [&](size_t bytes) -> char* {
    char* p = wsb + off; off += (bytes + 511) & ~(size_t)511; return p;
  };
  float* rel_e = (float*)walloc((size_t)E_DIR_ * D_ * 4);   // 400 MB
  float* acc   = (float*)walloc((size_t)N_ENT * D_ * 4);    // 160 MB
  float* norm1 = (float*)walloc((size_t)E_DIR_ * 4);
  float* norm2 = (float*)walloc((size_t)E_DIR_ * 4);
  int*   deg   = (int*)walloc((size_t)N_ENT * 4);
  float* rall1 = (float*)walloc((size_t)201 * D_ * 4);
  float* rall2 = (float*)walloc((size_t)201 * D_ * 4);
  unsigned short* wbp = (unsigned short*)walloc((size_t)10 * 208 * WLD_ * 2);
  if (off > ws_size) fprintf(stderr, "ws overflow: need %zu have %zu\n", off, ws_size);

  float* out   = (float*)d_out;
  float* x_out = out + OFS_X;
  float* r_out = out + OFS_R;

  auto WB = [&](int j) { return wbp + (size_t)j * 208 * WLD_; };

  WP10 wp; for (int j = 0; j < 10; j++) wp.p[j] = (const float*)d_in[2 + j];
  convert_weights<<<(10 * 208 * WLD_ + 255) / 256, 256, 0, stream>>>(wp, wbp);
  build_rall<<<(201 * D_ + 255) / 256, 256, 0, stream>>>(rel_embs, loop_rel1, rall1);

  const int* src1 = ei;
  const int* dst1 = ei + 2 * E_DIR_;
  const int* src2 = ei + E_DIR_;       // row0 second half = original dst
  const int* dst2 = ei + 3 * E_DIR_;   // row1 second half = original src

  int gE = (E_DIR_ + 255) / 256;
  hipMemsetAsync(deg, 0, (size_t)N_ENT * 4, stream);
  deg_count<<<gE, 256, 0, stream>>>(src1, deg, E_DIR_);
  norm_build<<<gE, 256, 0, stream>>>(src1, dst1, deg, norm1, E_DIR_);
  hipMemsetAsync(deg, 0, (size_t)N_ENT * 4, stream);
  deg_count<<<gE, 256, 0, stream>>>(src2, deg, E_DIR_);
  norm_build<<<gE, 256, 0, stream>>>(src2, dst2, deg, norm2, E_DIR_);

  const int* q_r   = quals;
  const int* q_e   = quals + 2 * NQ_;
  const int* q_eid = quals + 4 * NQ_;

  for (int layer = 0; layer < 2; layer++) {
    const float* x_in = layer ? (const float*)x_out : ent;
    const float* rall = layer ? rall2 : rall1;
    const float* lrel = layer ? loop_rel2 : loop_rel1;
    const float* bias = layer ? b2 : b1;
    const unsigned short* w_q    = WB(layer ? 9 : 4);
    const unsigned short* w_loop = WB(layer ? 7 : 2);
    const unsigned short* w_rel  = WB(layer ? 8 : 3);
    const unsigned short* w_d0   = WB(layer ? 5 : 0);  // w_in
    const unsigned short* w_d1   = WB(layer ? 6 : 1);  // w_out

    // r_next = rel_all[:200] @ w_rel
    float* r_dst = layer ? r_out : rall2;
    gemm_fused<3, 0><<<4, 256, 0, stream>>>(rall, nullptr, nullptr, nullptr, nullptr,
                                            w_rel, r_dst, nullptr, 1.0f, 200);
    if (layer == 0)
      copy_row<<<1, 256, 0, stream>>>(loop_rel2, rall2 + (size_t)200 * D_, D_);

    // loop_res -> acc (plain write, scale 1/3) -- initializes acc
    gemm_fused<2, 0><<<(N_ENT + 63) / 64, 256, 0, stream>>>(
        x_in, lrel, nullptr, nullptr, nullptr, w_loop, acc, nullptr, 1.0f / 3.0f, N_ENT);

    for (int dir = 0; dir < 2; dir++) {
      const int* et  = etype + dir * E_DIR_;
      const int* qr  = q_r + dir * NQ_;
      const int* qe  = q_e + dir * NQ_;
      const int* qid = q_eid + dir * NQ_;
      const int* s   = dir ? src2 : src1;
      const int* dd  = dir ? dst2 : dst1;
      const float* nm = dir ? norm2 : norm1;
      const unsigned short* wdir = dir ? w_d1 : w_d0;

      init_rel_e_k<<<(E_DIR_ * 50 + 255) / 256, 256, 0, stream>>>(rall, et, rel_e);
      gemm_fused<0, 1><<<(NQ_ + 63) / 64, 256, 0, stream>>>(
          x_in, rall, qe, qr, nullptr, w_q, rel_e, qid, 1.0f - ALPHA_MIX, NQ_);
      gemm_fused<1, 1><<<(E_DIR_ + 63) / 64, 256, 0, stream>>>(
          x_in, rel_e, s, nullptr, nm, wdir, acc, dd, 1.0f / 3.0f, E_DIR_);
    }
    final_tanh<<<(N_ENT * 50 + 255) / 256, 256, 0, stream>>>(acc, bias, x_out);
  }

  gather_out<<<(B_ * 14 * 50 + 255) / 256, 256, 0, stream>>>(
      x_out, r_out, ent_ix, rel_ix, quals_ix, out);
}

// Round 2
// 4194.544 us; speedup vs baseline: 1.2557x; 1.2557x over previous
//
#include <hip/hip_runtime.h>
#include <cstdio>

// ---------------------------------------------------------------------------
// Round 2: move segment-sums before the GEMMs (linearity), bf16 intermediates,
// pk-bf16 atomics.
//   rel_q[e]    = 0.2 * sum_{quals of e} (x[q_e]*rall[q_r]) @ w_q     (bf16)
//   node_pre[d] = sum_{e: dst=d} norm[e] * x[src[e]] * (0.8*rall[et[e]] + rel_q[e])
//   x_next      = tanh(( [pre_in|pre_out|x*loop] @ [w_in;w_out;w_loop] )/3 + b)
// ---------------------------------------------------------------------------

#define ALPHA_MIX 0.8f

constexpr int N_ENT  = 200000;
constexpr int D_     = 200;
constexpr int E_DIR_ = 500000;
constexpr int NQ_    = 400000;
constexpr int B_     = 4096;

constexpr int NT_  = 13;   // 13 column tiles of 16 (208 padded, 200 used)
constexpr int LDA_ = 232;  // LDS A row stride in bf16 elements
constexpr int WLD_ = 224;  // Bp row stride = padded K

constexpr size_t OFS_SUB  = 0;
constexpr size_t OFS_REL  = 819200;
constexpr size_t OFS_QOBJ = 1638400;
constexpr size_t OFS_QREL = 6553600;
constexpr size_t OFS_X    = 11468800;
constexpr size_t OFS_R    = 51468800;

typedef __bf16 bf16x8 __attribute__((ext_vector_type(8)));
typedef float  f32x4  __attribute__((ext_vector_type(4)));

__device__ __forceinline__ unsigned int f2bf(float f) {
  unsigned int u = __float_as_uint(f);
  u += 0x7FFFu + ((u >> 16) & 1u);   // RNE
  return u >> 16;
}
__device__ __forceinline__ unsigned long long pack4bf(float x, float y, float z, float w) {
  return (unsigned long long)f2bf(x) | ((unsigned long long)f2bf(y) << 16) |
         ((unsigned long long)f2bf(z) << 32) | ((unsigned long long)f2bf(w) << 48);
}
__device__ __forceinline__ float bf_lo(unsigned int u) { return __uint_as_float(u << 16); }
__device__ __forceinline__ float bf_hi(unsigned int u) { return __uint_as_float(u & 0xFFFF0000u); }
__device__ __forceinline__ unsigned int mulpk(unsigned int a, unsigned int b) {
  return f2bf(bf_lo(a) * bf_lo(b)) | (f2bf(bf_hi(a) * bf_hi(b)) << 16);
}

// packed bf16x2 atomic add (fire-and-forget)
typedef short v2s __attribute__((ext_vector_type(2)));
__device__ __forceinline__ void atomic_pk_add_bf16(unsigned short* addr, unsigned int pk) {
#if __has_builtin(__builtin_amdgcn_global_atomic_fadd_v2bf16)
  v2s v;
  __builtin_memcpy(&v, &pk, 4);
  __builtin_amdgcn_global_atomic_fadd_v2bf16(
      (__attribute__((address_space(1))) v2s*)(unsigned long long)addr, v);
#else
  unsigned int* ap = (unsigned int*)addr;
  unsigned int old = *ap;
  while (true) {
    unsigned int nv = f2bf(bf_lo(old) + bf_lo(pk)) | (f2bf(bf_hi(old) + bf_hi(pk)) << 16);
    unsigned int prev = atomicCAS(ap, old, nv);
    if (prev == old) break;
    old = prev;
  }
#endif
}

// ---------------------------------------------------------------------------
// Qual GEMM: rows = quals. A[row] = x_bf[q_e]*rall_bf[q_r]; epilogue scatters
// 0.2*A@w_q into rel_q[q_eid] with pk-bf16 atomics (cols paired via shfl).
// ---------------------------------------------------------------------------
__global__ __launch_bounds__(256)
void gemm_qual(const unsigned short* __restrict__ Xbf, const unsigned short* __restrict__ Rbf,
               const int* __restrict__ q_e, const int* __restrict__ q_r,
               const int* __restrict__ q_eid,
               const unsigned short* __restrict__ Bp,
               unsigned short* __restrict__ relq, int nrows)
{
  __shared__ __align__(16) unsigned short As[64 * LDA_];
  __shared__ int s_g[64], s_r[64], s_eid[64];

  const int t  = threadIdx.x;
  const int r0 = blockIdx.x * 64;

  if (t < 64) {
    int cr = min(r0 + t, nrows - 1);
    s_g[t] = q_e[cr]; s_r[t] = q_r[cr]; s_eid[t] = q_eid[cr];
  }
  __syncthreads();

  for (int task = t; task < 64 * 25; task += 256) {
    int i = task / 25, c = task % 25;
    uint4 xv = ((const uint4*)(Xbf + (size_t)s_g[i] * D_))[c];
    uint4 rv = ((const uint4*)(Rbf + (size_t)s_r[i] * D_))[c];
    uint4 o;
    o.x = mulpk(xv.x, rv.x); o.y = mulpk(xv.y, rv.y);
    o.z = mulpk(xv.z, rv.z); o.w = mulpk(xv.w, rv.w);
    *(uint4*)(As + i * LDA_ + c * 8) = o;
  }
  for (int task = t; task < 64 * 3; task += 256) {
    int i = task / 3, c = task % 3;
    *(uint4*)(As + i * LDA_ + 200 + c * 8) = make_uint4(0, 0, 0, 0);
  }
  __syncthreads();

  const int wave = t >> 6, lane = t & 63;
  const int m = lane & 15, quad = lane >> 4;

  f32x4 acc[NT_];
  const f32x4 zero = {0.f, 0.f, 0.f, 0.f};
  #pragma unroll
  for (int i = 0; i < NT_; i++) acc[i] = zero;

  const unsigned short* arow = As + (wave * 16 + m) * LDA_ + quad * 8;
  const unsigned short* brow = Bp + (size_t)m * WLD_ + quad * 8;

  #pragma unroll
  for (int ks = 0; ks < 7; ks++) {
    bf16x8 av = *(const bf16x8*)(arow + ks * 32);
    #pragma unroll
    for (int tt = 0; tt < NT_; tt++) {
      bf16x8 bv = *(const bf16x8*)(brow + (size_t)tt * 16 * WLD_ + ks * 32);
      acc[tt] = __builtin_amdgcn_mfma_f32_16x16x32_bf16(av, bv, acc[tt], 0, 0, 0);
    }
  }

  #pragma unroll
  for (int rg = 0; rg < 4; rg++) {
    int row = r0 + wave * 16 + quad * 4 + rg;
    bool valid = row < nrows;
    size_t orow = valid ? (size_t)s_eid[row - r0] * D_ : 0;
    #pragma unroll
    for (int tt = 0; tt < NT_; tt++) {
      float v  = acc[tt][rg] * (1.0f - ALPHA_MIX);
      float vn = __shfl_xor(v, 1);
      int col = tt * 16 + m;
      if (valid && !(m & 1) && col < D_) {
        unsigned int pk = f2bf(v) | (f2bf(vn) << 16);
        atomic_pk_add_bf16(relq + orow + col, pk);
      }
    }
  }
}

// ---------------------------------------------------------------------------
// Elementwise edge scatter: node_pre[dst] += norm * x_bf[src] * (0.8*rall + rel_q)
// one pk-bf16 atomic per thread (2 cols).
// ---------------------------------------------------------------------------
__global__ __launch_bounds__(256)
void scatter_edges(const unsigned short* __restrict__ relq,
                   const unsigned short* __restrict__ Xbf,
                   const float* __restrict__ rallf,
                   const int* __restrict__ src, const int* __restrict__ dst,
                   const int* __restrict__ et, const float* __restrict__ nrm,
                   unsigned short* __restrict__ pre)
{
  int i = blockIdx.x * 256 + threadIdx.x;
  if (i >= E_DIR_ * 100) return;
  int e = i / 100, c = i - e * 100;          // c = column pair index
  int s = src[e], d = dst[e], ty = et[e];
  float nm = nrm[e];
  unsigned int rq = *(const unsigned int*)(relq + (size_t)e * D_ + 2 * c);
  unsigned int xb = *(const unsigned int*)(Xbf + (size_t)s * D_ + 2 * c);
  float2 ra = *(const float2*)(rallf + (size_t)ty * D_ + 2 * c);
  float rl = ALPHA_MIX * ra.x + bf_lo(rq);
  float rh = ALPHA_MIX * ra.y + bf_hi(rq);
  float hl = nm * bf_lo(xb) * rl;
  float hh = nm * bf_hi(xb) * rh;
  atomic_pk_add_bf16(pre + (size_t)d * D_ + 2 * c, f2bf(hl) | (f2bf(hh) << 16));
}

// ---------------------------------------------------------------------------
// Node GEMM: 3 K-segments (pre_in, pre_out, x*loop_rel) accumulated into one
// fp32 acc; epilogue fuses /3 + bias + tanh, writes x fp32 (optional) + bf16.
// ---------------------------------------------------------------------------
__global__ __launch_bounds__(256)
void gemm_node(const unsigned short* __restrict__ pre0,
               const unsigned short* __restrict__ pre1,
               const unsigned short* __restrict__ xbf,
               const unsigned short* __restrict__ lrel,
               const unsigned short* __restrict__ B0,
               const unsigned short* __restrict__ B1,
               const unsigned short* __restrict__ B2,
               const float* __restrict__ bias,
               float* __restrict__ xo, unsigned short* __restrict__ xbf_out,
               int nrows)
{
  __shared__ __align__(16) unsigned short As[64 * LDA_];
  const int t  = threadIdx.x;
  const int r0 = blockIdx.x * 64;

  for (int task = t; task < 64 * 3; task += 256) {
    int i = task / 3, c = task % 3;
    *(uint4*)(As + i * LDA_ + 200 + c * 8) = make_uint4(0, 0, 0, 0);
  }

  const int wave = t >> 6, lane = t & 63;
  const int m = lane & 15, quad = lane >> 4;

  f32x4 acc[NT_];
  const f32x4 zero = {0.f, 0.f, 0.f, 0.f};
  #pragma unroll
  for (int i = 0; i < NT_; i++) acc[i] = zero;

  const unsigned short* Asrc[3] = {pre0, pre1, xbf};
  const unsigned short* Bsel[3] = {B0, B1, B2};

  #pragma unroll
  for (int seg = 0; seg < 3; seg++) {
    __syncthreads();
    for (int task = t; task < 64 * 25; task += 256) {
      int i = task / 25, c = task % 25;
      int cr = min(r0 + i, nrows - 1);
      uint4 vv = ((const uint4*)(Asrc[seg] + (size_t)cr * D_))[c];
      if (seg == 2) {
        uint4 lv = ((const uint4*)lrel)[c];
        vv.x = mulpk(vv.x, lv.x); vv.y = mulpk(vv.y, lv.y);
        vv.z = mulpk(vv.z, lv.z); vv.w = mulpk(vv.w, lv.w);
      }
      *(uint4*)(As + i * LDA_ + c * 8) = vv;
    }
    __syncthreads();

    const unsigned short* arow = As + (wave * 16 + m) * LDA_ + quad * 8;
    const unsigned short* brow = Bsel[seg] + (size_t)m * WLD_ + quad * 8;
    #pragma unroll
    for (int ks = 0; ks < 7; ks++) {
      bf16x8 av = *(const bf16x8*)(arow + ks * 32);
      #pragma unroll
      for (int tt = 0; tt < NT_; tt++) {
        bf16x8 bv = *(const bf16x8*)(brow + (size_t)tt * 16 * WLD_ + ks * 32);
        acc[tt] = __builtin_amdgcn_mfma_f32_16x16x32_bf16(av, bv, acc[tt], 0, 0, 0);
      }
    }
  }

  #pragma unroll
  for (int rg = 0; rg < 4; rg++) {
    int row = r0 + wave * 16 + quad * 4 + rg;
    if (row < nrows) {
      #pragma unroll
      for (int tt = 0; tt < NT_; tt++) {
        int col = tt * 16 + m;
        if (col < D_) {
          float v = acc[tt][rg] * (1.0f / 3.0f) + bias[col];
          float th = tanhf(v);
          if (xo) xo[(size_t)row * D_ + col] = th;
          xbf_out[(size_t)row * D_ + col] = (unsigned short)f2bf(th);
        }
      }
    }
  }
}

// ---------------------------------------------------------------------------
// Small GEMM for r_next (200 rows, fp32 in, fp32 out)
// ---------------------------------------------------------------------------
__global__ __launch_bounds__(256)
void gemm_rel200(const float* __restrict__ X, const unsigned short* __restrict__ Bp,
                 float* __restrict__ Out, int nrows)
{
  __shared__ __align__(16) unsigned short As[64 * LDA_];
  const int t  = threadIdx.x;
  const int r0 = blockIdx.x * 64;

  for (int task = t; task < 64 * 50; task += 256) {
    int i = task / 50, c = task % 50;
    int cr = min(r0 + i, nrows - 1);
    float4 xv = ((const float4*)(X + (size_t)cr * D_))[c];
    *(unsigned long long*)&As[i * LDA_ + c * 4] = pack4bf(xv.x, xv.y, xv.z, xv.w);
  }
  for (int task = t; task < 64 * 6; task += 256) {
    int i = task / 6, c = task % 6;
    *(unsigned long long*)&As[i * LDA_ + 200 + c * 4] = 0ull;
  }
  __syncthreads();

  const int wave = t >> 6, lane = t & 63;
  const int m = lane & 15, quad = lane >> 4;

  f32x4 acc[NT_];
  const f32x4 zero = {0.f, 0.f, 0.f, 0.f};
  #pragma unroll
  for (int i = 0; i < NT_; i++) acc[i] = zero;

  const unsigned short* arow = As + (wave * 16 + m) * LDA_ + quad * 8;
  const unsigned short* brow = Bp + (size_t)m * WLD_ + quad * 8;
  #pragma unroll
  for (int ks = 0; ks < 7; ks++) {
    bf16x8 av = *(const bf16x8*)(arow + ks * 32);
    #pragma unroll
    for (int tt = 0; tt < NT_; tt++) {
      bf16x8 bv = *(const bf16x8*)(brow + (size_t)tt * 16 * WLD_ + ks * 32);
      acc[tt] = __builtin_amdgcn_mfma_f32_16x16x32_bf16(av, bv, acc[tt], 0, 0, 0);
    }
  }

  #pragma unroll
  for (int rg = 0; rg < 4; rg++) {
    int row = r0 + wave * 16 + quad * 4 + rg;
    if (row < nrows) {
      #pragma unroll
      for (int tt = 0; tt < NT_; tt++) {
        int col = tt * 16 + m;
        if (col < D_) Out[(size_t)row * D_ + col] = acc[tt][rg];
      }
    }
  }
}

// ---------------------------------------------------------------------------
struct WP10 { const float* p[10]; };

__global__ void convert_weights(WP10 wp, unsigned short* __restrict__ wbp) {
  int i = blockIdx.x * 256 + threadIdx.x;
  if (i < 10 * 208 * WLD_) {
    int j = i / (208 * WLD_);
    int rem = i % (208 * WLD_);
    int n = rem / WLD_, k = rem % WLD_;
    float v = (n < D_ && k < D_) ? wp.p[j][(size_t)k * D_ + n] : 0.0f;  // Bp[n][k]=w[k][n]
    wbp[i] = (unsigned short)f2bf(v);
  }
}

__global__ void conv_f32_bf16_vec(const float* __restrict__ src,
                                  unsigned short* __restrict__ dst, int n4) {
  int i = blockIdx.x * 256 + threadIdx.x;
  if (i < n4) {
    float4 v = ((const float4*)src)[i];
    uint2 o;
    o.x = f2bf(v.x) | (f2bf(v.y) << 16);
    o.y = f2bf(v.z) | (f2bf(v.w) << 16);
    ((uint2*)dst)[i] = o;
  }
}

__global__ void build_rall(const float* __restrict__ rel_embs,
                           const float* __restrict__ loop_rel,
                           float* __restrict__ rall) {
  int i = blockIdx.x * 256 + threadIdx.x;
  if (i < 201 * D_) rall[i] = (i < 200 * D_) ? rel_embs[i] : loop_rel[i - 200 * D_];
}

__global__ void copy_row(const float* __restrict__ src, float* __restrict__ dst, int n) {
  int i = blockIdx.x * 256 + threadIdx.x;
  if (i < n) dst[i] = src[i];
}

__global__ void deg_count(const int* __restrict__ src, int* __restrict__ deg, int E) {
  int e = blockIdx.x * 256 + threadIdx.x;
  if (e < E) atomicAdd(&deg[src[e]], 1);
}

__global__ void norm_build(const int* __restrict__ src, const int* __restrict__ dst,
                           const int* __restrict__ deg, float* __restrict__ nrm, int E) {
  int e = blockIdx.x * 256 + threadIdx.x;
  if (e < E) {
    int a = deg[src[e]], b = deg[dst[e]];
    float fa = (a > 0) ? rsqrtf((float)a) : 0.0f;
    float fb = (b > 0) ? rsqrtf((float)b) : 0.0f;
    nrm[e] = fa * fb;
  }
}

__global__ void gather_out(const float* __restrict__ x2, const float* __restrict__ r2,
                           const int* __restrict__ ent_ix, const int* __restrict__ rel_ix,
                           const int* __restrict__ quals_ix, float* __restrict__ out) {
  int i = blockIdx.x * 256 + threadIdx.x;
  if (i >= B_ * 14 * 50) return;
  int b = i / 700, rem = i % 700, slot = rem / 50, c = rem % 50;
  const float* srcrow; float* dstrow;
  if (slot == 0)      { srcrow = x2 + (size_t)ent_ix[b] * D_;  dstrow = out + OFS_SUB + (size_t)b * D_; }
  else if (slot == 1) { srcrow = r2 + (size_t)rel_ix[b] * D_;  dstrow = out + OFS_REL + (size_t)b * D_; }
  else if (slot < 8)  { int j = slot - 2;
                        srcrow = x2 + (size_t)quals_ix[b * 12 + 2 * j + 1] * D_;
                        dstrow = out + OFS_QOBJ + ((size_t)b * 6 + j) * D_; }
  else                { int j = slot - 8;
                        srcrow = r2 + (size_t)quals_ix[b * 12 + 2 * j] * D_;
                        dstrow = out + OFS_QREL + ((size_t)b * 6 + j) * D_; }
  ((float4*)dstrow)[c] = ((const float4*)srcrow)[c];
}

// ---------------------------------------------------------------------------
extern "C" void kernel_launch(void* const* d_in, const int* in_sizes, int n_in,
                              void* d_out, int out_size, void* d_ws, size_t ws_size,
                              hipStream_t stream)
{
  const float* ent       = (const float*)d_in[0];
  const float* rel_embs  = (const float*)d_in[1];
  const float* loop_rel1 = (const float*)d_in[12];
  const float* loop_rel2 = (const float*)d_in[13];
  const float* b1        = (const float*)d_in[14];
  const float* b2        = (const float*)d_in[15];
  const int*   ei        = (const int*)d_in[16];
  const int*   etype     = (const int*)d_in[17];
  const int*   quals     = (const int*)d_in[18];
  const int*   ent_ix    = (const int*)d_in[19];
  const int*   rel_ix    = (const int*)d_in[20];
  const int*   quals_ix  = (const int*)d_in[21];

  char* wsb = (char*)d_ws;
  size_t off = 0;
  auto walloc = [&](size_t bytes) -> char* {
    char* p = wsb + off; off += (bytes + 511) & ~(size_t)511; return p;
  };
  unsigned short* relq  = (unsigned short*)walloc((size_t)E_DIR_ * D_ * 2);  // 200 MB
  unsigned short* pre0  = (unsigned short*)walloc((size_t)N_ENT * D_ * 2);   // 80 MB
  unsigned short* pre1  = (unsigned short*)walloc((size_t)N_ENT * D_ * 2);   // 80 MB
  unsigned short* x_bf  = (unsigned short*)walloc((size_t)N_ENT * D_ * 2);   // 80 MB
  float* norm1 = (float*)walloc((size_t)E_DIR_ * 4);
  float* norm2 = (float*)walloc((size_t)E_DIR_ * 4);
  int*   deg   = (int*)walloc((size_t)N_ENT * 4);
  float* rall1 = (float*)walloc((size_t)201 * D_ * 4);
  float* rall2 = (float*)walloc((size_t)201 * D_ * 4);
  unsigned short* rall1_bf = (unsigned short*)walloc((size_t)201 * D_ * 2);
  unsigned short* rall2_bf = (unsigned short*)walloc((size_t)201 * D_ * 2);
  unsigned short* lrel1_bf = (unsigned short*)walloc((size_t)D_ * 2);
  unsigned short* lrel2_bf = (unsigned short*)walloc((size_t)D_ * 2);
  unsigned short* wbp = (unsigned short*)walloc((size_t)10 * 208 * WLD_ * 2);
  if (off > ws_size) fprintf(stderr, "ws overflow: need %zu have %zu\n", off, ws_size);

  float* out   = (float*)d_out;
  float* x_out = out + OFS_X;
  float* r_out = out + OFS_R;

  auto WB = [&](int j) { return wbp + (size_t)j * 208 * WLD_; };

  WP10 wp; for (int j = 0; j < 10; j++) wp.p[j] = (const float*)d_in[2 + j];
  convert_weights<<<(10 * 208 * WLD_ + 255) / 256, 256, 0, stream>>>(wp, wbp);
  build_rall<<<(201 * D_ + 255) / 256, 256, 0, stream>>>(rel_embs, loop_rel1, rall1);
  conv_f32_bf16_vec<<<(201 * 50 + 255) / 256, 256, 0, stream>>>(rall1, rall1_bf, 201 * 50);
  conv_f32_bf16_vec<<<(N_ENT * 50 + 255) / 256, 256, 0, stream>>>(ent, x_bf, N_ENT * 50);
  conv_f32_bf16_vec<<<1, 256, 0, stream>>>(loop_rel1, lrel1_bf, 50);
  conv_f32_bf16_vec<<<1, 256, 0, stream>>>(loop_rel2, lrel2_bf, 50);

  const int* src1 = ei;
  const int* dst1 = ei + 2 * E_DIR_;
  const int* src2 = ei + E_DIR_;
  const int* dst2 = ei + 3 * E_DIR_;

  int gE = (E_DIR_ + 255) / 256;
  hipMemsetAsync(deg, 0, (size_t)N_ENT * 4, stream);
  deg_count<<<gE, 256, 0, stream>>>(src1, deg, E_DIR_);
  norm_build<<<gE, 256, 0, stream>>>(src1, dst1, deg, norm1, E_DIR_);
  hipMemsetAsync(deg, 0, (size_t)N_ENT * 4, stream);
  deg_count<<<gE, 256, 0, stream>>>(src2, deg, E_DIR_);
  norm_build<<<gE, 256, 0, stream>>>(src2, dst2, deg, norm2, E_DIR_);

  const int* q_r   = quals;
  const int* q_e   = quals + 2 * NQ_;
  const int* q_eid = quals + 4 * NQ_;

  for (int layer = 0; layer < 2; layer++) {
    const float* rallf = layer ? rall2 : rall1;
    const unsigned short* rallbf = layer ? rall2_bf : rall1_bf;
    const unsigned short* lrelbf = layer ? lrel2_bf : lrel1_bf;
    const float* bias = layer ? b2 : b1;
    const unsigned short* w_q    = WB(layer ? 9 : 4);
    const unsigned short* w_loop = WB(layer ? 7 : 2);
    const unsigned short* w_rel  = WB(layer ? 8 : 3);
    const unsigned short* w_in   = WB(layer ? 5 : 0);
    const unsigned short* w_out  = WB(layer ? 6 : 1);

    // r_next
    float* r_dst = layer ? r_out : rall2;
    gemm_rel200<<<4, 256, 0, stream>>>(rallf, w_rel, r_dst, 200);
    if (layer == 0) {
      copy_row<<<1, 256, 0, stream>>>(loop_rel2, rall2 + (size_t)200 * D_, D_);
      conv_f32_bf16_vec<<<(201 * 50 + 255) / 256, 256, 0, stream>>>(rall2, rall2_bf, 201 * 50);
    }

    hipMemsetAsync(pre0, 0, (size_t)N_ENT * D_ * 2, stream);
    hipMemsetAsync(pre1, 0, (size_t)N_ENT * D_ * 2, stream);

    for (int dir = 0; dir < 2; dir++) {
      const int* et  = etype + dir * E_DIR_;
      const int* qr  = q_r + dir * NQ_;
      const int* qe  = q_e + dir * NQ_;
      const int* qid = q_eid + dir * NQ_;
      const int* s   = dir ? src2 : src1;
      const int* dd  = dir ? dst2 : dst1;
      const float* nm = dir ? norm2 : norm1;
      unsigned short* pre = dir ? pre1 : pre0;

      hipMemsetAsync(relq, 0, (size_t)E_DIR_ * D_ * 2, stream);
      gemm_qual<<<(NQ_ + 63) / 64, 256, 0, stream>>>(x_bf, rallbf, qe, qr, qid, w_q, relq, NQ_);
      scatter_edges<<<(E_DIR_ * 100 + 255) / 256, 256, 0, stream>>>(
          relq, x_bf, rallf, s, dd, et, nm, pre);
    }

    gemm_node<<<(N_ENT + 63) / 64, 256, 0, stream>>>(
        pre0, pre1, x_bf, lrelbf, w_in, w_out, w_loop, bias,
        layer ? x_out : (float*)nullptr, x_bf, N_ENT);
  }

  gemm_rel200<<<4, 256, 0, stream>>>(rall2, WB(8), r_out, 200);
  gather_out<<<(B_ * 14 * 50 + 255) / 256, 256, 0, stream>>>(
      x_out, r_out, ent_ix, rel_ix, quals_ix, out);
}

// Round 3
// 3379.158 us; speedup vs baseline: 1.5587x; 1.2413x over previous
//
#include <hip/hip_runtime.h>
#include <cstdio>

// ---------------------------------------------------------------------------
// Round 3: delete relq (fold qual GEMM output straight into node_pre via
// epilogue scatter), replace edge scatter atomics with dst-CSR gather.
//   pre[d]  = sum_{e: dst=d} 0.8*norm[e]*x[src[e]]*rall[et[e]]   (node_gather,
//             CSR, fp32 accum, plain bf16 write -- no memset, no atomics)
//          += 0.2*norm[e]*x[src[e]] * ((x[q_e]*rall[q_r])@w_q)   (gemm_qual
//             epilogue pk-bf16 atomics, one per col pair)
//   x_next  = tanh(( [pre_in|pre_out|x*loop] @ [w_in;w_out;w_loop] )/3 + b)
// ---------------------------------------------------------------------------

#define ALPHA_MIX 0.8f

constexpr int N_ENT  = 200000;
constexpr int D_     = 200;
constexpr int E_DIR_ = 500000;
constexpr int NQ_    = 400000;
constexpr int B_     = 4096;

constexpr int NT_  = 13;   // 13 column tiles of 16 (208 padded, 200 used)
constexpr int LDA_ = 232;  // LDS A row stride in bf16 elements
constexpr int WLD_ = 224;  // Bp row stride = padded K

constexpr size_t OFS_SUB  = 0;
constexpr size_t OFS_REL  = 819200;
constexpr size_t OFS_QOBJ = 1638400;
constexpr size_t OFS_QREL = 6553600;
constexpr size_t OFS_X    = 11468800;
constexpr size_t OFS_R    = 51468800;

typedef __bf16 bf16x8 __attribute__((ext_vector_type(8)));
typedef float  f32x4  __attribute__((ext_vector_type(4)));

__device__ __forceinline__ unsigned int f2bf(float f) {
  unsigned int u = __float_as_uint(f);
  u += 0x7FFFu + ((u >> 16) & 1u);   // RNE
  return u >> 16;
}
__device__ __forceinline__ unsigned long long pack4bf(float x, float y, float z, float w) {
  return (unsigned long long)f2bf(x) | ((unsigned long long)f2bf(y) << 16) |
         ((unsigned long long)f2bf(z) << 32) | ((unsigned long long)f2bf(w) << 48);
}
__device__ __forceinline__ float bf_lo(unsigned int u) { return __uint_as_float(u << 16); }
__device__ __forceinline__ float bf_hi(unsigned int u) { return __uint_as_float(u & 0xFFFF0000u); }
__device__ __forceinline__ unsigned int mulpk(unsigned int a, unsigned int b) {
  return f2bf(bf_lo(a) * bf_lo(b)) | (f2bf(bf_hi(a) * bf_hi(b)) << 16);
}

typedef short v2s __attribute__((ext_vector_type(2)));
__device__ __forceinline__ void atomic_pk_add_bf16(unsigned short* addr, unsigned int pk) {
#if __has_builtin(__builtin_amdgcn_global_atomic_fadd_v2bf16)
  v2s v;
  __builtin_memcpy(&v, &pk, 4);
  __builtin_amdgcn_global_atomic_fadd_v2bf16(
      (__attribute__((address_space(1))) v2s*)(unsigned long long)addr, v);
#else
  unsigned int* ap = (unsigned int*)addr;
  unsigned int old = *ap;
  while (true) {
    unsigned int nv = f2bf(bf_lo(old) + bf_lo(pk)) | (f2bf(bf_hi(old) + bf_hi(pk)) << 16);
    unsigned int prev = atomicCAS(ap, old, nv);
    if (prev == old) break;
    old = prev;
  }
#endif
}

// ---------------------------------------------------------------------------
// Qual GEMM: rows = quals. A[row] = x_bf[q_e]*rall_bf[q_r]; y = A@w_q.
// Epilogue: pre[dst[eid]] += 0.2*norm[eid] * x_bf[src[eid]] * y   (pk atomics)
// ---------------------------------------------------------------------------
__global__ __launch_bounds__(256)
void gemm_qual(const unsigned short* __restrict__ Xbf, const unsigned short* __restrict__ Rbf,
               const int* __restrict__ q_e, const int* __restrict__ q_r,
               const int* __restrict__ q_eid,
               const int* __restrict__ srcv, const int* __restrict__ dstv,
               const float* __restrict__ nrm,
               const unsigned short* __restrict__ Bp,
               unsigned short* __restrict__ pre, int nrows)
{
  __shared__ __align__(16) unsigned short As[64 * LDA_];
  __shared__ int s_g[64], s_r[64], s_eid[64], s_dst[64];
  __shared__ float s_nm[64];

  const int t  = threadIdx.x;
  const int r0 = blockIdx.x * 64;

  if (t < 64) {
    int cr = min(r0 + t, nrows - 1);
    s_g[t] = q_e[cr]; s_r[t] = q_r[cr]; s_eid[t] = q_eid[cr];
  }
  __syncthreads();

  for (int task = t; task < 64 * 25; task += 256) {
    int i = task / 25, c = task % 25;
    uint4 xv = ((const uint4*)(Xbf + (size_t)s_g[i] * D_))[c];
    uint4 rv = ((const uint4*)(Rbf + (size_t)s_r[i] * D_))[c];
    uint4 o;
    o.x = mulpk(xv.x, rv.x); o.y = mulpk(xv.y, rv.y);
    o.z = mulpk(xv.z, rv.z); o.w = mulpk(xv.w, rv.w);
    *(uint4*)(As + i * LDA_ + c * 8) = o;
  }
  for (int task = t; task < 64 * 3; task += 256) {
    int i = task / 3, c = task % 3;
    *(uint4*)(As + i * LDA_ + 200 + c * 8) = make_uint4(0, 0, 0, 0);
  }
  __syncthreads();

  const int wave = t >> 6, lane = t & 63;
  const int m = lane & 15, quad = lane >> 4;

  f32x4 acc[NT_];
  const f32x4 zero = {0.f, 0.f, 0.f, 0.f};
  #pragma unroll
  for (int i = 0; i < NT_; i++) acc[i] = zero;

  {
    const unsigned short* arow = As + (wave * 16 + m) * LDA_ + quad * 8;
    const unsigned short* brow = Bp + (size_t)m * WLD_ + quad * 8;
    #pragma unroll
    for (int ks = 0; ks < 7; ks++) {
      bf16x8 av = *(const bf16x8*)(arow + ks * 32);
      #pragma unroll
      for (int tt = 0; tt < NT_; tt++) {
        bf16x8 bv = *(const bf16x8*)(brow + (size_t)tt * 16 * WLD_ + ks * 32);
        acc[tt] = __builtin_amdgcn_mfma_f32_16x16x32_bf16(av, bv, acc[tt], 0, 0, 0);
      }
    }
  }

  // restage LDS with x_bf[src[eid]] rows; gather edge metadata
  __syncthreads();
  if (t < 64) {
    int e = s_eid[t];
    s_dst[t] = dstv[e];
    s_nm[t]  = (1.0f - ALPHA_MIX) * nrm[e];
    s_g[t]   = srcv[e];
  }
  __syncthreads();
  for (int task = t; task < 64 * 25; task += 256) {
    int i = task / 25, c = task % 25;
    *(uint4*)(As + i * LDA_ + c * 8) = ((const uint4*)(Xbf + (size_t)s_g[i] * D_))[c];
  }
  __syncthreads();

  #pragma unroll
  for (int rg = 0; rg < 4; rg++) {
    int row = r0 + wave * 16 + quad * 4 + rg;
    bool valid = row < nrows;
    int li = row - r0;
    size_t orow = (size_t)s_dst[li] * D_;
    float nm = s_nm[li];
    #pragma unroll
    for (int tt = 0; tt < NT_; tt++) {
      int col = tt * 16 + m;
      float xv = (col < D_) ? __uint_as_float(((unsigned int)As[li * LDA_ + col]) << 16) : 0.0f;
      float v  = acc[tt][rg] * nm * xv;
      float vn = __shfl_xor(v, 1);
      if (valid && !(m & 1) && col < D_) {
        unsigned int pk = f2bf(v) | (f2bf(vn) << 16);
        atomic_pk_add_bf16(pre + orow + col, pk);
      }
    }
  }
}

// ---------------------------------------------------------------------------
// CSR-based node gather: pre[d] = 0.8 * sum_{e in(d)} norm*x[src]*rall[et]
// one wave per node, fp32 accumulation, plain bf16 write.
// ---------------------------------------------------------------------------
__global__ __launch_bounds__(256)
void node_gather(const int* __restrict__ starts, const int* __restrict__ csr,
                 const int* __restrict__ srcv, const int* __restrict__ et,
                 const float* __restrict__ nrm,
                 const unsigned short* __restrict__ xbf,
                 const unsigned short* __restrict__ rallbf,
                 unsigned short* __restrict__ pre)
{
  int node = blockIdx.x * 4 + (threadIdx.x >> 6);
  if (node >= N_ENT) return;
  int lane = threadIdx.x & 63;
  int p0 = starts[node], p1 = starts[node + 1];
  float a0 = 0.f, a1 = 0.f, a2 = 0.f, a3 = 0.f;
  for (int p = p0; p < p1; p++) {
    int e = csr[p];
    int s = srcv[e], ty = et[e];
    float nm = nrm[e];
    if (lane < 50) {
      uint2 xv = ((const uint2*)(xbf + (size_t)s * D_))[lane];
      uint2 rv = ((const uint2*)(rallbf + (size_t)ty * D_))[lane];
      a0 += nm * bf_lo(xv.x) * bf_lo(rv.x);
      a1 += nm * bf_hi(xv.x) * bf_hi(rv.x);
      a2 += nm * bf_lo(xv.y) * bf_lo(rv.y);
      a3 += nm * bf_hi(xv.y) * bf_hi(rv.y);
    }
  }
  if (lane < 50) {
    uint2 o;
    o.x = f2bf(a0 * ALPHA_MIX) | (f2bf(a1 * ALPHA_MIX) << 16);
    o.y = f2bf(a2 * ALPHA_MIX) | (f2bf(a3 * ALPHA_MIX) << 16);
    ((uint2*)(pre + (size_t)node * D_))[lane] = o;
  }
}

// ---------------------------------------------------------------------------
// Node GEMM: 3 K-segments (pre_in, pre_out, x*loop_rel); /3 + bias + tanh.
// ---------------------------------------------------------------------------
__global__ __launch_bounds__(256)
void gemm_node(const unsigned short* __restrict__ pre0,
               const unsigned short* __restrict__ pre1,
               const unsigned short* __restrict__ xbf,
               const unsigned short* __restrict__ lrel,
               const unsigned short* __restrict__ B0,
               const unsigned short* __restrict__ B1,
               const unsigned short* __restrict__ B2,
               const float* __restrict__ bias,
               float* __restrict__ xo, unsigned short* __restrict__ xbf_out,
               int nrows)
{
  __shared__ __align__(16) unsigned short As[64 * LDA_];
  const int t  = threadIdx.x;
  const int r0 = blockIdx.x * 64;

  for (int task = t; task < 64 * 3; task += 256) {
    int i = task / 3, c = task % 3;
    *(uint4*)(As + i * LDA_ + 200 + c * 8) = make_uint4(0, 0, 0, 0);
  }

  const int wave = t >> 6, lane = t & 63;
  const int m = lane & 15, quad = lane >> 4;

  f32x4 acc[NT_];
  const f32x4 zero = {0.f, 0.f, 0.f, 0.f};
  #pragma unroll
  for (int i = 0; i < NT_; i++) acc[i] = zero;

  const unsigned short* Asrc[3] = {pre0, pre1, xbf};
  const unsigned short* Bsel[3] = {B0, B1, B2};

  #pragma unroll
  for (int seg = 0; seg < 3; seg++) {
    __syncthreads();
    for (int task = t; task < 64 * 25; task += 256) {
      int i = task / 25, c = task % 25;
      int cr = min(r0 + i, nrows - 1);
      uint4 vv = ((const uint4*)(Asrc[seg] + (size_t)cr * D_))[c];
      if (seg == 2) {
        uint4 lv = ((const uint4*)lrel)[c];
        vv.x = mulpk(vv.x, lv.x); vv.y = mulpk(vv.y, lv.y);
        vv.z = mulpk(vv.z, lv.z); vv.w = mulpk(vv.w, lv.w);
      }
      *(uint4*)(As + i * LDA_ + c * 8) = vv;
    }
    __syncthreads();

    const unsigned short* arow = As + (wave * 16 + m) * LDA_ + quad * 8;
    const unsigned short* brow = Bsel[seg] + (size_t)m * WLD_ + quad * 8;
    #pragma unroll
    for (int ks = 0; ks < 7; ks++) {
      bf16x8 av = *(const bf16x8*)(arow + ks * 32);
      #pragma unroll
      for (int tt = 0; tt < NT_; tt++) {
        bf16x8 bv = *(const bf16x8*)(brow + (size_t)tt * 16 * WLD_ + ks * 32);
        acc[tt] = __builtin_amdgcn_mfma_f32_16x16x32_bf16(av, bv, acc[tt], 0, 0, 0);
      }
    }
  }

  #pragma unroll
  for (int rg = 0; rg < 4; rg++) {
    int row = r0 + wave * 16 + quad * 4 + rg;
    if (row < nrows) {
      #pragma unroll
      for (int tt = 0; tt < NT_; tt++) {
        int col = tt * 16 + m;
        if (col < D_) {
          float v = acc[tt][rg] * (1.0f / 3.0f) + bias[col];
          float th = tanhf(v);
          if (xo) xo[(size_t)row * D_ + col] = th;
          xbf_out[(size_t)row * D_ + col] = (unsigned short)f2bf(th);
        }
      }
    }
  }
}

// ---------------------------------------------------------------------------
__global__ __launch_bounds__(256)
void gemm_rel200(const float* __restrict__ X, const unsigned short* __restrict__ Bp,
                 float* __restrict__ Out, int nrows)
{
  __shared__ __align__(16) unsigned short As[64 * LDA_];
  const int t  = threadIdx.x;
  const int r0 = blockIdx.x * 64;

  for (int task = t; task < 64 * 50; task += 256) {
    int i = task / 50, c = task % 50;
    int cr = min(r0 + i, nrows - 1);
    float4 xv = ((const float4*)(X + (size_t)cr * D_))[c];
    *(unsigned long long*)&As[i * LDA_ + c * 4] = pack4bf(xv.x, xv.y, xv.z, xv.w);
  }
  for (int task = t; task < 64 * 6; task += 256) {
    int i = task / 6, c = task % 6;
    *(unsigned long long*)&As[i * LDA_ + 200 + c * 4] = 0ull;
  }
  __syncthreads();

  const int wave = t >> 6, lane = t & 63;
  const int m = lane & 15, quad = lane >> 4;

  f32x4 acc[NT_];
  const f32x4 zero = {0.f, 0.f, 0.f, 0.f};
  #pragma unroll
  for (int i = 0; i < NT_; i++) acc[i] = zero;

  const unsigned short* arow = As + (wave * 16 + m) * LDA_ + quad * 8;
  const unsigned short* brow = Bp + (size_t)m * WLD_ + quad * 8;
  #pragma unroll
  for (int ks = 0; ks < 7; ks++) {
    bf16x8 av = *(const bf16x8*)(arow + ks * 32);
    #pragma unroll
    for (int tt = 0; tt < NT_; tt++) {
      bf16x8 bv = *(const bf16x8*)(brow + (size_t)tt * 16 * WLD_ + ks * 32);
      acc[tt] = __builtin_amdgcn_mfma_f32_16x16x32_bf16(av, bv, acc[tt], 0, 0, 0);
    }
  }

  #pragma unroll
  for (int rg = 0; rg < 4; rg++) {
    int row = r0 + wave * 16 + quad * 4 + rg;
    if (row < nrows) {
      #pragma unroll
      for (int tt = 0; tt < NT_; tt++) {
        int col = tt * 16 + m;
        if (col < D_) Out[(size_t)row * D_ + col] = acc[tt][rg];
      }
    }
  }
}

// ---------------------------------------------------------------------------
struct WP10 { const float* p[10]; };

__global__ void convert_weights(WP10 wp, unsigned short* __restrict__ wbp) {
  int i = blockIdx.x * 256 + threadIdx.x;
  if (i < 10 * 208 * WLD_) {
    int j = i / (208 * WLD_);
    int rem = i % (208 * WLD_);
    int n = rem / WLD_, k = rem % WLD_;
    float v = (n < D_ && k < D_) ? wp.p[j][(size_t)k * D_ + n] : 0.0f;  // Bp[n][k]=w[k][n]
    wbp[i] = (unsigned short)f2bf(v);
  }
}

__global__ void conv_f32_bf16_vec(const float* __restrict__ src,
                                  unsigned short* __restrict__ dst, int n4) {
  int i = blockIdx.x * 256 + threadIdx.x;
  if (i < n4) {
    float4 v = ((const float4*)src)[i];
    uint2 o;
    o.x = f2bf(v.x) | (f2bf(v.y) << 16);
    o.y = f2bf(v.z) | (f2bf(v.w) << 16);
    ((uint2*)dst)[i] = o;
  }
}

__global__ void build_rall(const float* __restrict__ rel_embs,
                           const float* __restrict__ loop_rel,
                           float* __restrict__ rall) {
  int i = blockIdx.x * 256 + threadIdx.x;
  if (i < 201 * D_) rall[i] = (i < 200 * D_) ? rel_embs[i] : loop_rel[i - 200 * D_];
}

__global__ void copy_row(const float* __restrict__ src, float* __restrict__ dst, int n) {
  int i = blockIdx.x * 256 + threadIdx.x;
  if (i < n) dst[i] = src[i];
}

__global__ void deg_count(const int* __restrict__ src, int* __restrict__ deg, int E) {
  int e = blockIdx.x * 256 + threadIdx.x;
  if (e < E) atomicAdd(&deg[src[e]], 1);
}

__global__ void norm_build(const int* __restrict__ src, const int* __restrict__ dst,
                           const int* __restrict__ deg, float* __restrict__ nrm, int E) {
  int e = blockIdx.x * 256 + threadIdx.x;
  if (e < E) {
    int a = deg[src[e]], b = deg[dst[e]];
    float fa = (a > 0) ? rsqrtf((float)a) : 0.0f;
    float fb = (b > 0) ? rsqrtf((float)b) : 0.0f;
    nrm[e] = fa * fb;
  }
}

// ---- exclusive scan (3 kernels) + CSR fill -------------------------------
constexpr int SCHUNK = 2048;

__global__ void scan_partial(const int* __restrict__ in, int* __restrict__ part, int n) {
  __shared__ int red[256];
  int b = blockIdx.x, t = threadIdx.x;
  int base = b * SCHUNK + t * 8;
  int s = 0;
  #pragma unroll
  for (int j = 0; j < 8; j++) { int i = base + j; if (i < n) s += in[i]; }
  red[t] = s; __syncthreads();
  for (int off = 128; off > 0; off >>= 1) {
    if (t < off) red[t] += red[t + off];
    __syncthreads();
  }
  if (t == 0) part[b] = red[0];
}

__global__ void scan_part_seq(int* part, int nb) {
  if (threadIdx.x == 0 && blockIdx.x == 0) {
    int run = 0;
    for (int i = 0; i < nb; i++) { int v = part[i]; part[i] = run; run += v; }
  }
}

__global__ void scan_final(const int* __restrict__ in, const int* __restrict__ part,
                           int* __restrict__ outs, int* __restrict__ cursor,
                           int n, int total) {
  __shared__ int buf[256];
  int b = blockIdx.x, t = threadIdx.x;
  int base = b * SCHUNK + t * 8;
  int v[8]; int s = 0;
  #pragma unroll
  for (int j = 0; j < 8; j++) { int i = base + j; v[j] = (i < n) ? in[i] : 0; s += v[j]; }
  buf[t] = s; __syncthreads();
  for (int off = 1; off < 256; off <<= 1) {
    int add = (t >= off) ? buf[t - off] : 0;
    __syncthreads();
    buf[t] += add;
    __syncthreads();
  }
  int excl = buf[t] - s + part[b];
  #pragma unroll
  for (int j = 0; j < 8; j++) {
    int i = base + j;
    if (i < n) { outs[i] = excl; cursor[i] = excl; }
    excl += v[j];
  }
  if (b == 0 && t == 0) outs[n] = total;
}

__global__ void fill_csr(const int* __restrict__ dstv, int* __restrict__ cursor,
                         int* __restrict__ csr, int E) {
  int e = blockIdx.x * 256 + threadIdx.x;
  if (e < E) {
    int pos = atomicAdd(&cursor[dstv[e]], 1);
    csr[pos] = e;
  }
}

__global__ void gather_out(const float* __restrict__ x2, const float* __restrict__ r2,
                           const int* __restrict__ ent_ix, const int* __restrict__ rel_ix,
                           const int* __restrict__ quals_ix, float* __restrict__ out) {
  int i = blockIdx.x * 256 + threadIdx.x;
  if (i >= B_ * 14 * 50) return;
  int b = i / 700, rem = i % 700, slot = rem / 50, c = rem % 50;
  const float* srcrow; float* dstrow;
  if (slot == 0)      { srcrow = x2 + (size_t)ent_ix[b] * D_;  dstrow = out + OFS_SUB + (size_t)b * D_; }
  else if (slot == 1) { srcrow = r2 + (size_t)rel_ix[b] * D_;  dstrow = out + OFS_REL + (size_t)b * D_; }
  else if (slot < 8)  { int j = slot - 2;
                        srcrow = x2 + (size_t)quals_ix[b * 12 + 2 * j + 1] * D_;
                        dstrow = out + OFS_QOBJ + ((size_t)b * 6 + j) * D_; }
  else                { int j = slot - 8;
                        srcrow = r2 + (size_t)quals_ix[b * 12 + 2 * j] * D_;
                        dstrow = out + OFS_QREL + ((size_t)b * 6 + j) * D_; }
  ((float4*)dstrow)[c] = ((const float4*)srcrow)[c];
}

// ---------------------------------------------------------------------------
extern "C" void kernel_launch(void* const* d_in, const int* in_sizes, int n_in,
                              void* d_out, int out_size, void* d_ws, size_t ws_size,
                              hipStream_t stream)
{
  const float* ent       = (const float*)d_in[0];
  const float* rel_embs  = (const float*)d_in[1];
  const float* loop_rel1 = (const float*)d_in[12];
  const float* loop_rel2 = (const float*)d_in[13];
  const float* b1        = (const float*)d_in[14];
  const float* b2        = (const float*)d_in[15];
  const int*   ei        = (const int*)d_in[16];
  const int*   etype     = (const int*)d_in[17];
  const int*   quals     = (const int*)d_in[18];
  const int*   ent_ix    = (const int*)d_in[19];
  const int*   rel_ix    = (const int*)d_in[20];
  const int*   quals_ix  = (const int*)d_in[21];

  char* wsb = (char*)d_ws;
  size_t off = 0;
  auto walloc = [&](size_t bytes) -> char* {
    char* p = wsb + off; off += (bytes + 511) & ~(size_t)511; return p;
  };
  unsigned short* pre0  = (unsigned short*)walloc((size_t)N_ENT * D_ * 2);   // 80 MB
  unsigned short* pre1  = (unsigned short*)walloc((size_t)N_ENT * D_ * 2);   // 80 MB
  unsigned short* x_bf  = (unsigned short*)walloc((size_t)N_ENT * D_ * 2);   // 80 MB
  float* norm1 = (float*)walloc((size_t)E_DIR_ * 4);
  float* norm2 = (float*)walloc((size_t)E_DIR_ * 4);
  int*   degA  = (int*)walloc((size_t)N_ENT * 4);   // counts of orig src
  int*   degB  = (int*)walloc((size_t)N_ENT * 4);   // counts of orig dst
  int*   starts0 = (int*)walloc((size_t)(N_ENT + 1) * 4);
  int*   starts1 = (int*)walloc((size_t)(N_ENT + 1) * 4);
  int*   cursor0 = (int*)walloc((size_t)N_ENT * 4);
  int*   cursor1 = (int*)walloc((size_t)N_ENT * 4);
  int*   csr0    = (int*)walloc((size_t)E_DIR_ * 4);
  int*   csr1    = (int*)walloc((size_t)E_DIR_ * 4);
  int*   part    = (int*)walloc((size_t)256 * 4);
  float* rall1 = (float*)walloc((size_t)201 * D_ * 4);
  float* rall2 = (float*)walloc((size_t)201 * D_ * 4);
  unsigned short* rall1_bf = (unsigned short*)walloc((size_t)201 * D_ * 2);
  unsigned short* rall2_bf = (unsigned short*)walloc((size_t)201 * D_ * 2);
  unsigned short* lrel1_bf = (unsigned short*)walloc((size_t)D_ * 2);
  unsigned short* lrel2_bf = (unsigned short*)walloc((size_t)D_ * 2);
  unsigned short* wbp = (unsigned short*)walloc((size_t)10 * 208 * WLD_ * 2);
  if (off > ws_size) fprintf(stderr, "ws overflow: need %zu have %zu\n", off, ws_size);

  float* out   = (float*)d_out;
  float* x_out = out + OFS_X;
  float* r_out = out + OFS_R;

  auto WB = [&](int j) { return wbp + (size_t)j * 208 * WLD_; };

  WP10 wp; for (int j = 0; j < 10; j++) wp.p[j] = (const float*)d_in[2 + j];
  convert_weights<<<(10 * 208 * WLD_ + 255) / 256, 256, 0, stream>>>(wp, wbp);
  build_rall<<<(201 * D_ + 255) / 256, 256, 0, stream>>>(rel_embs, loop_rel1, rall1);
  conv_f32_bf16_vec<<<(201 * 50 + 255) / 256, 256, 0, stream>>>(rall1, rall1_bf, 201 * 50);
  conv_f32_bf16_vec<<<(N_ENT * 50 + 255) / 256, 256, 0, stream>>>(ent, x_bf, N_ENT * 50);
  conv_f32_bf16_vec<<<1, 256, 0, stream>>>(loop_rel1, lrel1_bf, 50);
  conv_f32_bf16_vec<<<1, 256, 0, stream>>>(loop_rel2, lrel2_bf, 50);

  const int* src1 = ei;                // dir0 src = orig src
  const int* dst1 = ei + 2 * E_DIR_;   // dir0 dst = orig dst
  const int* src2 = ei + E_DIR_;       // dir1 src = orig dst
  const int* dst2 = ei + 3 * E_DIR_;   // dir1 dst = orig src

  int gE = (E_DIR_ + 255) / 256;
  hipMemsetAsync(degA, 0, (size_t)N_ENT * 4, stream);
  hipMemsetAsync(degB, 0, (size_t)N_ENT * 4, stream);
  deg_count<<<gE, 256, 0, stream>>>(src1, degA, E_DIR_);   // counts(orig src)
  deg_count<<<gE, 256, 0, stream>>>(src2, degB, E_DIR_);   // counts(orig dst)
  norm_build<<<gE, 256, 0, stream>>>(src1, dst1, degA, norm1, E_DIR_);
  norm_build<<<gE, 256, 0, stream>>>(src2, dst2, degB, norm2, E_DIR_);

  // CSR by dst. dir0 indeg = counts(dst1) = degB; dir1 indeg = counts(dst2) = degA.
  int nbScan = (N_ENT + SCHUNK - 1) / SCHUNK;
  scan_partial<<<nbScan, 256, 0, stream>>>(degB, part, N_ENT);
  scan_part_seq<<<1, 64, 0, stream>>>(part, nbScan);
  scan_final<<<nbScan, 256, 0, stream>>>(degB, part, starts0, cursor0, N_ENT, E_DIR_);
  fill_csr<<<gE, 256, 0, stream>>>(dst1, cursor0, csr0, E_DIR_);

  scan_partial<<<nbScan, 256, 0, stream>>>(degA, part, N_ENT);
  scan_part_seq<<<1, 64, 0, stream>>>(part, nbScan);
  scan_final<<<nbScan, 256, 0, stream>>>(degA, part, starts1, cursor1, N_ENT, E_DIR_);
  fill_csr<<<gE, 256, 0, stream>>>(dst2, cursor1, csr1, E_DIR_);

  const int* q_r   = quals;
  const int* q_e   = quals + 2 * NQ_;
  const int* q_eid = quals + 4 * NQ_;

  for (int layer = 0; layer < 2; layer++) {
    const float* rallf = layer ? rall2 : rall1;
    const unsigned short* rallbf = layer ? rall2_bf : rall1_bf;
    const unsigned short* lrelbf = layer ? lrel2_bf : lrel1_bf;
    const float* bias = layer ? b2 : b1;
    const unsigned short* w_q    = WB(layer ? 9 : 4);
    const unsigned short* w_loop = WB(layer ? 7 : 2);
    const unsigned short* w_rel  = WB(layer ? 8 : 3);
    const unsigned short* w_in   = WB(layer ? 5 : 0);
    const unsigned short* w_out  = WB(layer ? 6 : 1);

    float* r_dst = layer ? r_out : rall2;
    gemm_rel200<<<4, 256, 0, stream>>>(rallf, w_rel, r_dst, 200);
    if (layer == 0) {
      copy_row<<<1, 256, 0, stream>>>(loop_rel2, rall2 + (size_t)200 * D_, D_);
      conv_f32_bf16_vec<<<(201 * 50 + 255) / 256, 256, 0, stream>>>(rall2, rall2_bf, 201 * 50);
    }

    for (int dir = 0; dir < 2; dir++) {
      const int* et  = etype + dir * E_DIR_;
      const int* qr  = q_r + dir * NQ_;
      const int* qe  = q_e + dir * NQ_;
      const int* qid = q_eid + dir * NQ_;
      const int* s   = dir ? src2 : src1;
      const int* dd  = dir ? dst2 : dst1;
      const float* nm = dir ? norm2 : norm1;
      const int* sts = dir ? starts1 : starts0;
      const int* csr = dir ? csr1 : csr0;
      unsigned short* pre = dir ? pre1 : pre0;

      node_gather<<<(N_ENT + 3) / 4, 256, 0, stream>>>(sts, csr, s, et, nm, x_bf, rallbf, pre);
      gemm_qual<<<(NQ_ + 63) / 64, 256, 0, stream>>>(x_bf, rallbf, qe, qr, qid,
                                                     s, dd, nm, w_q, pre, NQ_);
    }

    gemm_node<<<(N_ENT + 63) / 64, 256, 0, stream>>>(
        pre0, pre1, x_bf, lrelbf, w_in, w_out, w_loop, bias,
        layer ? x_out : (float*)nullptr, x_bf, N_ENT);
  }

  gather_out<<<(B_ * 14 * 50 + 255) / 256, 256, 0, stream>>>(
      x_out, r_out, ent_ix, rel_ix, quals_ix, out);
}